// Round 24
// baseline (126.947 us; speedup 1.0000x reference)
//
#include <hip/hip_runtime.h>
#include <hip/hip_bf16.h>

// Fused causal self-attention (GQA) for MI355X/gfx950.
// Shapes: B=2, T=2048, C=1024, H=16, Hkv=4, D=64.
// Round 24: R23 + adjacent-tile pairing. Block's wave-groups own q-tiles
// (2p+1, 2p) -> loop bound 2p+2, group B idles exactly 1 iter (98% util vs
// R23's 67%); per-bh wave-iters -31%, staging -31%. Complementary grid:
// block c and c+256 bounds sum to uniform 34/CU. All else R23-verbatim.

typedef __attribute__((ext_vector_type(8))) short s16x8;   // 8 x bf16 raw
typedef __attribute__((ext_vector_type(4))) float f32x4;
typedef __attribute__((ext_vector_type(4))) unsigned short u16x4;

#define LOG2E 1.44269504088896340736f

__device__ __forceinline__ float bf2f(unsigned short u) {
  unsigned int i = ((unsigned int)u) << 16;
  return __builtin_bit_cast(float, i);
}
__device__ __forceinline__ unsigned short f2bf(float f) {
  unsigned int i = __builtin_bit_cast(unsigned int, f);
  i += 0x7fffu + ((i >> 16) & 1u);   // RNE
  return (unsigned short)(i >> 16);
}
__device__ __forceinline__ unsigned int cvtpk(float lo, float hi) {
  unsigned int r;                    // low half <- lo, high half <- hi (HW-verified)
  asm("v_cvt_pk_bf16_f32 %0, %1, %2" : "=v"(r) : "v"(lo), "v"(hi));
  return r;
}

__device__ __forceinline__ void async16(const void* g, void* l) {
  __builtin_amdgcn_global_load_lds(
      (const __attribute__((address_space(1))) void*)g,
      (__attribute__((address_space(3))) void*)l, 16, 0, 0);
}

// ---------------- prep kernels ----------------

__global__ void conv_f32_to_bf16(const float* __restrict__ in,
                                 unsigned short* __restrict__ out, int n) {
  int i = (blockIdx.x * blockDim.x + threadIdx.x) * 4;
  if (i + 3 < n) {
    float4 v = *(const float4*)(in + i);
    u16x4 o = { f2bf(v.x), f2bf(v.y), f2bf(v.z), f2bf(v.w) };
    *(u16x4*)(out + i) = o;
  }
}

// Batched: W [1024][N_z] fp32 -> Wt [N_z][1024] bf16 for 4 weights in one
// launch (z selects matrix). N: Wq=1024, Wk=256, Wv=256, Wo=1024.
__global__ void transpose_conv4(const float* __restrict__ W0,
                                const float* __restrict__ W1,
                                const float* __restrict__ W2,
                                const float* __restrict__ W3,
                                unsigned short* __restrict__ D0,
                                unsigned short* __restrict__ D1,
                                unsigned short* __restrict__ D2,
                                unsigned short* __restrict__ D3) {
  __shared__ float tile[32][33];
  int z = blockIdx.z;
  const float* W = (z == 0) ? W0 : (z == 1) ? W1 : (z == 2) ? W2 : W3;
  unsigned short* Wt = (z == 0) ? D0 : (z == 1) ? D1 : (z == 2) ? D2 : D3;
  int N = (z == 1 || z == 2) ? 256 : 1024;
  const int K = 1024;
  int n0 = blockIdx.x * 32, k0 = blockIdx.y * 32;
  if (n0 >= N) return;
  int tx = threadIdx.x, ty = threadIdx.y;
  for (int i = ty; i < 32; i += 8)
    tile[i][tx] = W[(size_t)(k0 + i) * N + n0 + tx];
  __syncthreads();
  for (int i = ty; i < 32; i += 8)
    Wt[(size_t)(n0 + i) * K + k0 + tx] = f2bf(tile[tx][i]);
}

// RoPE on packed QKV [4096][1536]: heads 0..15 = Q scaled 0.125*log2(e)
// (softmax runs in exp2 domain), heads 16..19 = K at col offset 1024.
__global__ void rope_qk(unsigned short* __restrict__ QKV,
                        const float* __restrict__ cosb,
                        const float* __restrict__ sinb) {
  int idx = blockIdx.x * blockDim.x + threadIdx.x;
  int d = idx & 31;
  int hh = (idx >> 5) % 20;
  int row = idx / (32 * 20);
  int t = row & 2047;
  size_t base;
  float mul;
  if (hh < 16) { base = (size_t)row * 1536 + hh * 64 + d;   mul = 0.125f * LOG2E; }
  else         { base = (size_t)row * 1536 + 1024 + (hh - 16) * 64 + d; mul = 1.0f; }
  float x1 = bf2f(QKV[base]), x2 = bf2f(QKV[base + 32]);
  float c = cosb[t * 32 + d], s = sinb[t * 32 + d];
  QKV[base]      = f2bf((x1 * c + x2 * s) * mul);
  QKV[base + 32] = f2bf((-x1 * s + x2 * c) * mul);
}

// ---------------- GEMM: C[M,N] = A[M,K] * Bt[N,K]^T (R19 verbatim) ----------------
__global__ __launch_bounds__(256) void gemm_bt(
    const unsigned short* __restrict__ A, const unsigned short* __restrict__ Bt,
    void* __restrict__ Cp, int M, int N, int K, int c_f32) {
  __shared__ unsigned short As[128 * 64];   // 16 KB
  __shared__ unsigned short Bs[64 * 64];    // 8 KB
  int tid = threadIdx.x;
  int w = tid >> 6, l = tid & 63, g = l >> 4, lr = l & 15;
  int wr = w >> 1, wc = w & 1;

  // XCD-chunked remap (gridDim.x % 8 == 0 -> bijective)
  int nb = gridDim.x, bid = blockIdx.x;
  int wg = (bid & 7) * (nb >> 3) + (bid >> 3);
  int nx = N >> 6;
  int m0 = (wg / nx) * 128, n0 = (wg % nx) * 64;
  int sk = lr & 7;   // fragment-read swizzle key

  f32x4 acc[4][2] = {};

  for (int k0 = 0; k0 < K; k0 += 64) {
#pragma unroll
    for (int i = 0; i < 4; ++i) {
      int c = i * 256 + tid;             // 16B unit index, 8 units/row
      int row = c >> 3, srcu = ((c & 7) ^ (row & 7)) * 8;
      async16(A + (size_t)(m0 + row) * K + k0 + srcu, (char*)As + c * 16);
    }
#pragma unroll
    for (int i = 0; i < 2; ++i) {
      int c = i * 256 + tid;
      int row = c >> 3, srcu = ((c & 7) ^ (row & 7)) * 8;
      async16(Bt + (size_t)(n0 + row) * K + k0 + srcu, (char*)Bs + c * 16);
    }
    __syncthreads();

    s16x8 af[2][4], bfr[2][2];
#pragma unroll
    for (int ks = 0; ks < 2; ++ks) {
#pragma unroll
      for (int m = 0; m < 4; ++m)
        af[ks][m] = *(const s16x8*)(As + (wr * 64 + m * 16 + lr) * 64 +
                                    ((ks * 4 + g) ^ sk) * 8);
#pragma unroll
      for (int n = 0; n < 2; ++n)
        bfr[ks][n] = *(const s16x8*)(Bs + (wc * 32 + n * 16 + lr) * 64 +
                                     ((ks * 4 + g) ^ sk) * 8);
    }
#pragma unroll
    for (int ks = 0; ks < 2; ++ks)
#pragma unroll
      for (int m = 0; m < 4; ++m)
#pragma unroll
        for (int n = 0; n < 2; ++n)
          acc[m][n] = __builtin_amdgcn_mfma_f32_16x16x32_bf16(
              af[ks][m], bfr[ks][n], acc[m][n], 0, 0, 0);
    __syncthreads();
  }

  // C/D layout: row = (l>>4)*4 + r, col = l&15  [HW-verified]
  if (c_f32) {
    float* C = (float*)Cp;
#pragma unroll
    for (int m = 0; m < 4; ++m)
#pragma unroll
      for (int n = 0; n < 2; ++n)
#pragma unroll
        for (int r = 0; r < 4; ++r)
          C[(size_t)(m0 + wr * 64 + m * 16 + g * 4 + r) * N +
            n0 + wc * 32 + n * 16 + lr] = acc[m][n][r];
  } else {
    unsigned short* C = (unsigned short*)Cp;
#pragma unroll
    for (int m = 0; m < 4; ++m)
#pragma unroll
      for (int n = 0; n < 2; ++n)
#pragma unroll
        for (int r = 0; r < 4; ++r)
          C[(size_t)(m0 + wr * 64 + m * 16 + g * 4 + r) * N +
            n0 + wc * 32 + n * 16 + lr] = f2bf(acc[m][n][r]);
  }
}

// ---------------- flash attention (8-wave q-split, adjacent pairing) ----------------
// 512 blocks x 512 threads. Block -> adjacent q-tile pair (2p+1, 2p), loop
// bound 2p+2; group 0 (waves 0-3) = tile 2p+1 (active all iters), group 1
// (waves 4-7) = tile 2p (idles exactly 1 iter). Grid: block c<256 takes
// p=15-(c>>5) (heavy), block c+256 takes p=(c-256)>>5 (light) -> per-CU
// depth uniform 34. Per-wave body R19/R23-verbatim.
__global__ __launch_bounds__(512, 4) void attn_fused(
    const unsigned short* __restrict__ QKV, unsigned short* __restrict__ Y) {
  __shared__ unsigned short Kt[2][64 * 64];   // [kv][d], swizzled (16 KB)
  __shared__ unsigned short Vt[2][64 * 64];   // [d][kv], swizzled (16 KB)
  __shared__ unsigned short Pb[8][16 * 64];   // per-wave P [q][kv] (16 KB)

  const int T = 2048, CS = 1536;
  int tid = threadIdx.x;
  int w = tid >> 6, l = tid & 63, g = l >> 4, lr = l & 15;
  int gw = w >> 2, ws = w & 3;         // wave-group, wave-in-group
  int n = blockIdx.x;
  int p, bh;
  if (n < 256) { p = 15 - (n >> 5);    bh = n & 31; }
  else         { p = (n - 256) >> 5;   bh = (n - 256) & 31; }
  int qtA = 2 * p + 1, qtB = 2 * p;
  int b = bh >> 4, h = bh & 15, kvh = h >> 2;
  int sx = lr & 7;

  const unsigned short* Qp = QKV + (size_t)b * T * CS + h * 64;
  const unsigned short* Kp = QKV + (size_t)b * T * CS + 1024 + kvh * 64;
  const unsigned short* Vp = QKV + (size_t)b * T * CS + 1280 + kvh * 64;
  unsigned short* Pw = Pb[w];

  // V staging decode (512 threads): thread owns kv-pair (kvE,kvE+1) x 4 d.
  // Store rule Vt[d][kv ^ ((d&7)*8)] preserved; b32-packed writes.
  int kvE = (tid & 31) * 2, dcV = ((tid >> 5) & 15) * 4;

  int qt = (gw == 0) ? qtA : qtB;      // this wave's q-tile
  int qw = qt * 64 + ws * 16;
  int q_mine = qw + lr;                // this lane's q-row

  s16x8 qf[2];
#pragma unroll
  for (int ks = 0; ks < 2; ++ks)
    qf[ks] = *(const s16x8*)(Qp + (size_t)q_mine * CS + ks * 32 + g * 8);

  f32x4 o[4] = {};
  float mrun = -1e30f, lrun = 0.f;
  int ntiles = qtA + 1;                // block-uniform loop bound (= 2p+2)

  // ---- prologue: stage tile 0 into buffer 0 (512 threads) ----
  {
    int c = tid;                       // 512 x 16B = 8 KB K tile
    int row = c >> 3, srcc = ((c & 7) ^ (row & 7)) * 8;
    async16(Kp + (size_t)row * CS + srcc, (char*)(&Kt[0][0]) + c * 16);
  }
  {
    u16x4 vE = *(const u16x4*)(Vp + (size_t)kvE * CS + dcV);
    u16x4 vO = *(const u16x4*)(Vp + (size_t)(kvE + 1) * CS + dcV);
#pragma unroll
    for (int j4 = 0; j4 < 4; ++j4) {
      int d = dcV + j4;
      unsigned int pk = (unsigned int)(unsigned short)vE[j4] |
                        ((unsigned int)(unsigned short)vO[j4] << 16);
      *(unsigned int*)(&Vt[0][0] + d * 64 + (kvE ^ ((d & 7) * 8))) = pk;
    }
  }
  __syncthreads();

  int cur = 0;
  for (int it = 0; it < ntiles; ++it) {
    int kv0 = it * 64;
    bool hasnext = (it + 1 < ntiles);
    bool act = (it <= qt);             // wave-uniform (gw0: always true)

    // ---- T14 stage: issue next tile's K (async->LDS) and V (->regs) ----
    u16x4 vE, vO;
    if (hasnext) {
      int kvn = kv0 + 64;
      int c = tid;
      int row = c >> 3, srcc = ((c & 7) ^ (row & 7)) * 8;
      async16(Kp + (size_t)(kvn + row) * CS + srcc,
              (char*)(&Kt[cur ^ 1][0]) + c * 16);
      vE = *(const u16x4*)(Vp + (size_t)(kvn + kvE) * CS + dcV);
      vO = *(const u16x4*)(Vp + (size_t)(kvn + kvE + 1) * CS + dcV);
    }

    if (act) {
      // ---- S^T = K Q^T: lane holds S[q_mine][kv = nf*16 + g*4 + r] ----
      const unsigned short* Kc = &Kt[cur][0];
      const unsigned short* Vc = &Vt[cur][0];
      f32x4 s[4];
      __builtin_amdgcn_s_setprio(1);
#pragma unroll
      for (int nf = 0; nf < 4; ++nf) {
        f32x4 z = {};
#pragma unroll
        for (int ks = 0; ks < 2; ++ks) {
          s16x8 kf = *(const s16x8*)(Kc + (nf * 16 + lr) * 64 +
                                     ((ks * 4 + g) ^ sx) * 8);
          z = __builtin_amdgcn_mfma_f32_16x16x32_bf16(kf, qf[ks], z, 0, 0, 0);
        }
        s[nf] = z;
      }
      __builtin_amdgcn_s_setprio(0);

      if (it == qt) {   // this wave-group's diagonal tile: causal mask
#pragma unroll
        for (int nf = 0; nf < 4; ++nf)
#pragma unroll
          for (int r = 0; r < 4; ++r)
            if (kv0 + nf * 16 + g * 4 + r > q_mine) s[nf][r] = -1e30f;
      }

      // ---- softmax (exp2 domain): 16 in-lane values + 2 shuffles ----
      float mt = s[0][0];
#pragma unroll
      for (int nf = 0; nf < 4; ++nf)
#pragma unroll
        for (int r = 0; r < 4; ++r) mt = fmaxf(mt, s[nf][r]);
      mt = fmaxf(mt, __shfl_xor(mt, 16, 64));
      mt = fmaxf(mt, __shfl_xor(mt, 32, 64));

      if (__any(mt > mrun + 11.5416f)) {   // defer-max (8 nats in log2 units)
        float mnew = fmaxf(mrun, mt);
        float corr = exp2f(mrun - mnew);
        float psum = 0.f;
#pragma unroll
        for (int nf = 0; nf < 4; ++nf)
#pragma unroll
          for (int r = 0; r < 4; ++r) {
            float p2 = exp2f(s[nf][r] - mnew);
            s[nf][r] = p2;
            psum += p2;
          }
        psum += __shfl_xor(psum, 16, 64);
        psum += __shfl_xor(psum, 32, 64);
        lrun = lrun * corr + psum;
        mrun = mnew;
#pragma unroll
        for (int r = 0; r < 4; ++r) {
          float cr = __shfl(corr, g * 4 + r, 64);
#pragma unroll
          for (int d0 = 0; d0 < 4; ++d0) o[d0][r] *= cr;
        }
      } else {                         // fast path: no rescale
        float psum = 0.f;
#pragma unroll
        for (int nf = 0; nf < 4; ++nf)
#pragma unroll
          for (int r = 0; r < 4; ++r) {
            float p2 = exp2f(s[nf][r] - mrun);
            s[nf][r] = p2;
            psum += p2;
          }
        psum += __shfl_xor(psum, 16, 64);
        psum += __shfl_xor(psum, 32, 64);
        lrun += psum;
      }

      // ---- P -> LDS [q=lr][kv] via cvt_pk (b64 writes; RNE identical) ----
#pragma unroll
      for (int nf = 0; nf < 4; ++nf) {
        uint2 pv;
        pv.x = cvtpk(s[nf][0], s[nf][1]);
        pv.y = cvtpk(s[nf][2], s[nf][3]);
        *(uint2*)(Pw + lr * 64 + ((nf * 16 + g * 4) ^ (sx * 8))) = pv;
      }
      asm volatile("s_waitcnt lgkmcnt(0)" ::: "memory");
      __builtin_amdgcn_sched_barrier(0);   // rule #18

      s16x8 pf[2];
#pragma unroll
      for (int ks = 0; ks < 2; ++ks)
        pf[ks] = *(const s16x8*)(Pw + lr * 64 + ((ks * 4 + g) ^ sx) * 8);
      __builtin_amdgcn_s_setprio(1);
#pragma unroll
      for (int d0 = 0; d0 < 4; ++d0)
#pragma unroll
        for (int ks = 0; ks < 2; ++ks) {
          s16x8 vf = *(const s16x8*)(Vc + (d0 * 16 + lr) * 64 +
                                     ((ks * 4 + g) ^ sx) * 8);
          o[d0] = __builtin_amdgcn_mfma_f32_16x16x32_bf16(pf[ks], vf, o[d0], 0, 0, 0);
        }
      __builtin_amdgcn_s_setprio(0);
    }

    // ---- write staged V regs -> back buffer (4x b32 packed, all threads) ----
    if (hasnext) {
      unsigned short* Vn = &Vt[cur ^ 1][0];
#pragma unroll
      for (int j4 = 0; j4 < 4; ++j4) {
        int d = dcV + j4;
        unsigned int pk = (unsigned int)(unsigned short)vE[j4] |
                          ((unsigned int)(unsigned short)vO[j4] << 16);
        *(unsigned int*)(Vn + d * 64 + (kvE ^ ((d & 7) * 8))) = pk;
      }
    }
    __syncthreads();   // drains vmcnt (K async) + lgkm (V writes)
    cur ^= 1;
  }

  // ---- epilogue: o rows are g*4+r; lrun lives at lane (*, lr=g*4+r) ----
#pragma unroll
  for (int r = 0; r < 4; ++r) {
    float lv = __shfl(lrun, g * 4 + r, 64);
    float inv = 1.f / lv;
    size_t rowoff = (size_t)(b * T + qw + g * 4 + r) * 1024 + h * 64;
#pragma unroll
    for (int d0 = 0; d0 < 4; ++d0)
      Y[rowoff + d0 * 16 + lr] = f2bf(o[d0][r] * inv);
  }
}

// ---------------- launch ----------------

extern "C" void kernel_launch(void* const* d_in, const int* in_sizes, int n_in,
                              void* d_out, int out_size, void* d_ws, size_t ws_size,
                              hipStream_t stream) {
  const float* x    = (const float*)d_in[0];
  const float* cosb = (const float*)d_in[1];
  const float* sinb = (const float*)d_in[2];
  const float* Wq   = (const float*)d_in[3];
  const float* Wk   = (const float*)d_in[4];
  const float* Wv   = (const float*)d_in[5];
  const float* Wo   = (const float*)d_in[6];
  float* out = (float*)d_out;

  // Buffer map:
  //   d_out (16 MB): QKVb [4096][1536] bf16 = 12 MB  (dead at final gemm)
  //   d_ws: xb 0..8M | Wqkvt 8..11M | Wot 11..13M ; Yb aliases xb after attn
  char* ob = (char*)d_out;
  char* ws = (char*)d_ws;
  const size_t MB = 1024 * 1024;
  unsigned short* QKVb  = (unsigned short*)(ob);
  unsigned short* xb    = (unsigned short*)(ws);
  unsigned short* Wqkvt = (unsigned short*)(ws + 8 * MB);
  unsigned short* Wot   = (unsigned short*)(ws + 11 * MB);
  unsigned short* Yb    = xb;   // x-content dead after QKV gemm

  conv_f32_to_bf16<<<4096, 256, 0, stream>>>(x, xb, 4096 * 1024);
  // pack W_qkv^T rows: [0,1024) = Wq, [1024,1280) = Wk, [1280,1536) = Wv
  transpose_conv4<<<dim3(32, 32, 4), dim3(32, 8), 0, stream>>>(
      Wq, Wk, Wv, Wo,
      Wqkvt, Wqkvt + (size_t)1024 * 1024, Wqkvt + (size_t)1280 * 1024, Wot);

  // fused QKV projection: [4096][1536] bf16 (768 blocks, XCD-chunked)
  gemm_bt<<<dim3(768), 256, 0, stream>>>(xb, Wqkvt, QKVb, 4096, 1536, 1024, 0);

  // RoPE on Q (x0.125*log2e) + K in one pass
  rope_qk<<<10240, 256, 0, stream>>>(QKVb, cosb, sinb);

  // attention -> Yb bf16 [B*T][1024]  (8-wave adjacent-pair blocks)
  attn_fused<<<dim3(512), 512, 0, stream>>>(QKVb, Yb);

  // output projection (fp32, overwrites d_out; 512 blocks, XCD-chunked)
  gemm_bt<<<dim3(512), 256, 0, stream>>>(Yb, Wot, out, 4096, 1024, 1024, 1);
}

// Round 25
// 118.055 us; speedup vs baseline: 1.0753x; 1.0753x over previous
//
#include <hip/hip_runtime.h>
#include <hip/hip_bf16.h>

// Fused causal self-attention (GQA) for MI355X/gfx950.
// Shapes: B=2, T=2048, C=1024, H=16, Hkv=4, D=64.
// Round 25: revert to R23 (best measured: 118.3 us total, attn 62.2).
// R24's adjacent pairing cut work 31% but collapsed tail concurrency
// (occupancy 34->24%) — third confirmation that concurrency dominates work
// count in this latency-bound regime. R23 configuration:
//   - attn: 512 blocks x 512 threads (8 waves); wave-group q-split
//     (waves 0-3 = heavy tile 31-j, waves 4-7 = light tile j) sharing one
//     K/V double-buffered staging pipeline; per-wave body = R19
//     (swapped-QK^T lane-local softmax in exp2 domain, defer-max, cvt_pk
//     P-pack, b32 V-packs, rule-18 fence)
//   - fused QKV gemm + out-proj (128x64, BK=64, XCD-chunked), batched
//     weight transposes, fused QK RoPE (LOG2E folded into Q scale)

typedef __attribute__((ext_vector_type(8))) short s16x8;   // 8 x bf16 raw
typedef __attribute__((ext_vector_type(4))) float f32x4;
typedef __attribute__((ext_vector_type(4))) unsigned short u16x4;

#define LOG2E 1.44269504088896340736f

__device__ __forceinline__ float bf2f(unsigned short u) {
  unsigned int i = ((unsigned int)u) << 16;
  return __builtin_bit_cast(float, i);
}
__device__ __forceinline__ unsigned short f2bf(float f) {
  unsigned int i = __builtin_bit_cast(unsigned int, f);
  i += 0x7fffu + ((i >> 16) & 1u);   // RNE
  return (unsigned short)(i >> 16);
}
__device__ __forceinline__ unsigned int cvtpk(float lo, float hi) {
  unsigned int r;                    // low half <- lo, high half <- hi (HW-verified)
  asm("v_cvt_pk_bf16_f32 %0, %1, %2" : "=v"(r) : "v"(lo), "v"(hi));
  return r;
}

__device__ __forceinline__ void async16(const void* g, void* l) {
  __builtin_amdgcn_global_load_lds(
      (const __attribute__((address_space(1))) void*)g,
      (__attribute__((address_space(3))) void*)l, 16, 0, 0);
}

// ---------------- prep kernels ----------------

__global__ void conv_f32_to_bf16(const float* __restrict__ in,
                                 unsigned short* __restrict__ out, int n) {
  int i = (blockIdx.x * blockDim.x + threadIdx.x) * 4;
  if (i + 3 < n) {
    float4 v = *(const float4*)(in + i);
    u16x4 o = { f2bf(v.x), f2bf(v.y), f2bf(v.z), f2bf(v.w) };
    *(u16x4*)(out + i) = o;
  }
}

// Batched: W [1024][N_z] fp32 -> Wt [N_z][1024] bf16 for 4 weights in one
// launch (z selects matrix). N: Wq=1024, Wk=256, Wv=256, Wo=1024.
__global__ void transpose_conv4(const float* __restrict__ W0,
                                const float* __restrict__ W1,
                                const float* __restrict__ W2,
                                const float* __restrict__ W3,
                                unsigned short* __restrict__ D0,
                                unsigned short* __restrict__ D1,
                                unsigned short* __restrict__ D2,
                                unsigned short* __restrict__ D3) {
  __shared__ float tile[32][33];
  int z = blockIdx.z;
  const float* W = (z == 0) ? W0 : (z == 1) ? W1 : (z == 2) ? W2 : W3;
  unsigned short* Wt = (z == 0) ? D0 : (z == 1) ? D1 : (z == 2) ? D2 : D3;
  int N = (z == 1 || z == 2) ? 256 : 1024;
  const int K = 1024;
  int n0 = blockIdx.x * 32, k0 = blockIdx.y * 32;
  if (n0 >= N) return;
  int tx = threadIdx.x, ty = threadIdx.y;
  for (int i = ty; i < 32; i += 8)
    tile[i][tx] = W[(size_t)(k0 + i) * N + n0 + tx];
  __syncthreads();
  for (int i = ty; i < 32; i += 8)
    Wt[(size_t)(n0 + i) * K + k0 + tx] = f2bf(tile[tx][i]);
}

// RoPE on packed QKV [4096][1536]: heads 0..15 = Q scaled 0.125*log2(e)
// (softmax runs in exp2 domain), heads 16..19 = K at col offset 1024.
__global__ void rope_qk(unsigned short* __restrict__ QKV,
                        const float* __restrict__ cosb,
                        const float* __restrict__ sinb) {
  int idx = blockIdx.x * blockDim.x + threadIdx.x;
  int d = idx & 31;
  int hh = (idx >> 5) % 20;
  int row = idx / (32 * 20);
  int t = row & 2047;
  size_t base;
  float mul;
  if (hh < 16) { base = (size_t)row * 1536 + hh * 64 + d;   mul = 0.125f * LOG2E; }
  else         { base = (size_t)row * 1536 + 1024 + (hh - 16) * 64 + d; mul = 1.0f; }
  float x1 = bf2f(QKV[base]), x2 = bf2f(QKV[base + 32]);
  float c = cosb[t * 32 + d], s = sinb[t * 32 + d];
  QKV[base]      = f2bf((x1 * c + x2 * s) * mul);
  QKV[base + 32] = f2bf((-x1 * s + x2 * c) * mul);
}

// ---------------- GEMM: C[M,N] = A[M,K] * Bt[N,K]^T (R19 verbatim) ----------------
__global__ __launch_bounds__(256) void gemm_bt(
    const unsigned short* __restrict__ A, const unsigned short* __restrict__ Bt,
    void* __restrict__ Cp, int M, int N, int K, int c_f32) {
  __shared__ unsigned short As[128 * 64];   // 16 KB
  __shared__ unsigned short Bs[64 * 64];    // 8 KB
  int tid = threadIdx.x;
  int w = tid >> 6, l = tid & 63, g = l >> 4, lr = l & 15;
  int wr = w >> 1, wc = w & 1;

  // XCD-chunked remap (gridDim.x % 8 == 0 -> bijective)
  int nb = gridDim.x, bid = blockIdx.x;
  int wg = (bid & 7) * (nb >> 3) + (bid >> 3);
  int nx = N >> 6;
  int m0 = (wg / nx) * 128, n0 = (wg % nx) * 64;
  int sk = lr & 7;   // fragment-read swizzle key

  f32x4 acc[4][2] = {};

  for (int k0 = 0; k0 < K; k0 += 64) {
#pragma unroll
    for (int i = 0; i < 4; ++i) {
      int c = i * 256 + tid;             // 16B unit index, 8 units/row
      int row = c >> 3, srcu = ((c & 7) ^ (row & 7)) * 8;
      async16(A + (size_t)(m0 + row) * K + k0 + srcu, (char*)As + c * 16);
    }
#pragma unroll
    for (int i = 0; i < 2; ++i) {
      int c = i * 256 + tid;
      int row = c >> 3, srcu = ((c & 7) ^ (row & 7)) * 8;
      async16(Bt + (size_t)(n0 + row) * K + k0 + srcu, (char*)Bs + c * 16);
    }
    __syncthreads();

    s16x8 af[2][4], bfr[2][2];
#pragma unroll
    for (int ks = 0; ks < 2; ++ks) {
#pragma unroll
      for (int m = 0; m < 4; ++m)
        af[ks][m] = *(const s16x8*)(As + (wr * 64 + m * 16 + lr) * 64 +
                                    ((ks * 4 + g) ^ sk) * 8);
#pragma unroll
      for (int n = 0; n < 2; ++n)
        bfr[ks][n] = *(const s16x8*)(Bs + (wc * 32 + n * 16 + lr) * 64 +
                                     ((ks * 4 + g) ^ sk) * 8);
    }
#pragma unroll
    for (int ks = 0; ks < 2; ++ks)
#pragma unroll
      for (int m = 0; m < 4; ++m)
#pragma unroll
        for (int n = 0; n < 2; ++n)
          acc[m][n] = __builtin_amdgcn_mfma_f32_16x16x32_bf16(
              af[ks][m], bfr[ks][n], acc[m][n], 0, 0, 0);
    __syncthreads();
  }

  // C/D layout: row = (l>>4)*4 + r, col = l&15  [HW-verified]
  if (c_f32) {
    float* C = (float*)Cp;
#pragma unroll
    for (int m = 0; m < 4; ++m)
#pragma unroll
      for (int n = 0; n < 2; ++n)
#pragma unroll
        for (int r = 0; r < 4; ++r)
          C[(size_t)(m0 + wr * 64 + m * 16 + g * 4 + r) * N +
            n0 + wc * 32 + n * 16 + lr] = acc[m][n][r];
  } else {
    unsigned short* C = (unsigned short*)Cp;
#pragma unroll
    for (int m = 0; m < 4; ++m)
#pragma unroll
      for (int n = 0; n < 2; ++n)
#pragma unroll
        for (int r = 0; r < 4; ++r)
          C[(size_t)(m0 + wr * 64 + m * 16 + g * 4 + r) * N +
            n0 + wc * 32 + n * 16 + lr] = f2bf(acc[m][n][r]);
  }
}

// ---------------- flash attention (8-wave q-split, shared K/V staging) ----------------
// 512 blocks x 512 threads. Block -> q-tile pair (qtA=31-j, qtB=j); first
// 256 blocks j=n>>5 (heavy-first), second 256 j=15-... so paired blocks on a
// CU sum to uniform depth. Wave-group 0 (waves 0-3) computes tile A over all
// ntiles=qtA+1 iters; group 1 (waves 4-7) computes tile B while it<=qtB
// (wave-uniform predicate; it keeps staging + barriers afterward).
// Per-wave body = R19 verbatim. Lane (g,lr) holds S[q=qw+lr][kv=nf*16+g*4+r].
__global__ __launch_bounds__(512, 4) void attn_fused(
    const unsigned short* __restrict__ QKV, unsigned short* __restrict__ Y) {
  __shared__ unsigned short Kt[2][64 * 64];   // [kv][d], swizzled (16 KB)
  __shared__ unsigned short Vt[2][64 * 64];   // [d][kv], swizzled (16 KB)
  __shared__ unsigned short Pb[8][16 * 64];   // per-wave P [q][kv] (16 KB)

  const int T = 2048, CS = 1536;
  int tid = threadIdx.x;
  int w = tid >> 6, l = tid & 63, g = l >> 4, lr = l & 15;
  int gw = w >> 2, ws = w & 3;         // wave-group, wave-in-group
  int n = blockIdx.x;
  int j, bh;
  if (n < 256) { j = n >> 5;                bh = n & 31; }
  else         { j = 15 - ((n - 256) >> 5); bh = (n - 256) & 31; }
  int qtA = 31 - j, qtB = j;
  int b = bh >> 4, h = bh & 15, kvh = h >> 2;
  int sx = lr & 7;

  const unsigned short* Qp = QKV + (size_t)b * T * CS + h * 64;
  const unsigned short* Kp = QKV + (size_t)b * T * CS + 1024 + kvh * 64;
  const unsigned short* Vp = QKV + (size_t)b * T * CS + 1280 + kvh * 64;
  unsigned short* Pw = Pb[w];

  // V staging decode (512 threads): thread owns kv-pair (kvE,kvE+1) x 4 d.
  // Store rule Vt[d][kv ^ ((d&7)*8)] preserved; b32-packed writes.
  int kvE = (tid & 31) * 2, dcV = ((tid >> 5) & 15) * 4;

  int qt = (gw == 0) ? qtA : qtB;      // this wave's q-tile
  int qw = qt * 64 + ws * 16;
  int q_mine = qw + lr;                // this lane's q-row

  s16x8 qf[2];
#pragma unroll
  for (int ks = 0; ks < 2; ++ks)
    qf[ks] = *(const s16x8*)(Qp + (size_t)q_mine * CS + ks * 32 + g * 8);

  f32x4 o[4] = {};
  float mrun = -1e30f, lrun = 0.f;
  int ntiles = qtA + 1;                // block-uniform loop bound

  // ---- prologue: stage tile 0 into buffer 0 (512 threads) ----
  {
    int c = tid;                       // 512 x 16B = 8 KB K tile
    int row = c >> 3, srcc = ((c & 7) ^ (row & 7)) * 8;
    async16(Kp + (size_t)row * CS + srcc, (char*)(&Kt[0][0]) + c * 16);
  }
  {
    u16x4 vE = *(const u16x4*)(Vp + (size_t)kvE * CS + dcV);
    u16x4 vO = *(const u16x4*)(Vp + (size_t)(kvE + 1) * CS + dcV);
#pragma unroll
    for (int j4 = 0; j4 < 4; ++j4) {
      int d = dcV + j4;
      unsigned int pk = (unsigned int)(unsigned short)vE[j4] |
                        ((unsigned int)(unsigned short)vO[j4] << 16);
      *(unsigned int*)(&Vt[0][0] + d * 64 + (kvE ^ ((d & 7) * 8))) = pk;
    }
  }
  __syncthreads();

  int cur = 0;
  for (int it = 0; it < ntiles; ++it) {
    int kv0 = it * 64;
    bool hasnext = (it + 1 < ntiles);
    bool act = (it <= qt);             // wave-uniform (gw0: always true)

    // ---- T14 stage: issue next tile's K (async->LDS) and V (->regs) ----
    u16x4 vE, vO;
    if (hasnext) {
      int kvn = kv0 + 64;
      int c = tid;
      int row = c >> 3, srcc = ((c & 7) ^ (row & 7)) * 8;
      async16(Kp + (size_t)(kvn + row) * CS + srcc,
              (char*)(&Kt[cur ^ 1][0]) + c * 16);
      vE = *(const u16x4*)(Vp + (size_t)(kvn + kvE) * CS + dcV);
      vO = *(const u16x4*)(Vp + (size_t)(kvn + kvE + 1) * CS + dcV);
    }

    if (act) {
      // ---- S^T = K Q^T: lane holds S[q_mine][kv = nf*16 + g*4 + r] ----
      const unsigned short* Kc = &Kt[cur][0];
      const unsigned short* Vc = &Vt[cur][0];
      f32x4 s[4];
      __builtin_amdgcn_s_setprio(1);
#pragma unroll
      for (int nf = 0; nf < 4; ++nf) {
        f32x4 z = {};
#pragma unroll
        for (int ks = 0; ks < 2; ++ks) {
          s16x8 kf = *(const s16x8*)(Kc + (nf * 16 + lr) * 64 +
                                     ((ks * 4 + g) ^ sx) * 8);
          z = __builtin_amdgcn_mfma_f32_16x16x32_bf16(kf, qf[ks], z, 0, 0, 0);
        }
        s[nf] = z;
      }
      __builtin_amdgcn_s_setprio(0);

      if (it == qt) {   // this wave-group's diagonal tile: causal mask
#pragma unroll
        for (int nf = 0; nf < 4; ++nf)
#pragma unroll
          for (int r = 0; r < 4; ++r)
            if (kv0 + nf * 16 + g * 4 + r > q_mine) s[nf][r] = -1e30f;
      }

      // ---- softmax (exp2 domain): 16 in-lane values + 2 shuffles ----
      float mt = s[0][0];
#pragma unroll
      for (int nf = 0; nf < 4; ++nf)
#pragma unroll
        for (int r = 0; r < 4; ++r) mt = fmaxf(mt, s[nf][r]);
      mt = fmaxf(mt, __shfl_xor(mt, 16, 64));
      mt = fmaxf(mt, __shfl_xor(mt, 32, 64));

      if (__any(mt > mrun + 11.5416f)) {   // defer-max (8 nats in log2 units)
        float mnew = fmaxf(mrun, mt);
        float corr = exp2f(mrun - mnew);
        float psum = 0.f;
#pragma unroll
        for (int nf = 0; nf < 4; ++nf)
#pragma unroll
          for (int r = 0; r < 4; ++r) {
            float p = exp2f(s[nf][r] - mnew);
            s[nf][r] = p;
            psum += p;
          }
        psum += __shfl_xor(psum, 16, 64);
        psum += __shfl_xor(psum, 32, 64);
        lrun = lrun * corr + psum;
        mrun = mnew;
#pragma unroll
        for (int r = 0; r < 4; ++r) {
          float cr = __shfl(corr, g * 4 + r, 64);
#pragma unroll
          for (int d0 = 0; d0 < 4; ++d0) o[d0][r] *= cr;
        }
      } else {                         // fast path: no rescale
        float psum = 0.f;
#pragma unroll
        for (int nf = 0; nf < 4; ++nf)
#pragma unroll
          for (int r = 0; r < 4; ++r) {
            float p = exp2f(s[nf][r] - mrun);
            s[nf][r] = p;
            psum += p;
          }
        psum += __shfl_xor(psum, 16, 64);
        psum += __shfl_xor(psum, 32, 64);
        lrun += psum;
      }

      // ---- P -> LDS [q=lr][kv] via cvt_pk (b64 writes; RNE identical) ----
#pragma unroll
      for (int nf = 0; nf < 4; ++nf) {
        uint2 pv;
        pv.x = cvtpk(s[nf][0], s[nf][1]);
        pv.y = cvtpk(s[nf][2], s[nf][3]);
        *(uint2*)(Pw + lr * 64 + ((nf * 16 + g * 4) ^ (sx * 8))) = pv;
      }
      asm volatile("s_waitcnt lgkmcnt(0)" ::: "memory");
      __builtin_amdgcn_sched_barrier(0);   // rule #18

      s16x8 pf[2];
#pragma unroll
      for (int ks = 0; ks < 2; ++ks)
        pf[ks] = *(const s16x8*)(Pw + lr * 64 + ((ks * 4 + g) ^ sx) * 8);
      __builtin_amdgcn_s_setprio(1);
#pragma unroll
      for (int d0 = 0; d0 < 4; ++d0)
#pragma unroll
        for (int ks = 0; ks < 2; ++ks) {
          s16x8 vf = *(const s16x8*)(Vc + (d0 * 16 + lr) * 64 +
                                     ((ks * 4 + g) ^ sx) * 8);
          o[d0] = __builtin_amdgcn_mfma_f32_16x16x32_bf16(pf[ks], vf, o[d0], 0, 0, 0);
        }
      __builtin_amdgcn_s_setprio(0);
    }

    // ---- write staged V regs -> back buffer (4x b32 packed, all threads) ----
    if (hasnext) {
      unsigned short* Vn = &Vt[cur ^ 1][0];
#pragma unroll
      for (int j4 = 0; j4 < 4; ++j4) {
        int d = dcV + j4;
        unsigned int pk = (unsigned int)(unsigned short)vE[j4] |
                          ((unsigned int)(unsigned short)vO[j4] << 16);
        *(unsigned int*)(Vn + d * 64 + (kvE ^ ((d & 7) * 8))) = pk;
      }
    }
    __syncthreads();   // drains vmcnt (K async) + lgkm (V writes)
    cur ^= 1;
  }

  // ---- epilogue: o rows are g*4+r; lrun lives at lane (*, lr=g*4+r) ----
#pragma unroll
  for (int r = 0; r < 4; ++r) {
    float lv = __shfl(lrun, g * 4 + r, 64);
    float inv = 1.f / lv;
    size_t rowoff = (size_t)(b * T + qw + g * 4 + r) * 1024 + h * 64;
#pragma unroll
    for (int d0 = 0; d0 < 4; ++d0)
      Y[rowoff + d0 * 16 + lr] = f2bf(o[d0][r] * inv);
  }
}

// ---------------- launch ----------------

extern "C" void kernel_launch(void* const* d_in, const int* in_sizes, int n_in,
                              void* d_out, int out_size, void* d_ws, size_t ws_size,
                              hipStream_t stream) {
  const float* x    = (const float*)d_in[0];
  const float* cosb = (const float*)d_in[1];
  const float* sinb = (const float*)d_in[2];
  const float* Wq   = (const float*)d_in[3];
  const float* Wk   = (const float*)d_in[4];
  const float* Wv   = (const float*)d_in[5];
  const float* Wo   = (const float*)d_in[6];
  float* out = (float*)d_out;

  // Buffer map:
  //   d_out (16 MB): QKVb [4096][1536] bf16 = 12 MB  (dead at final gemm)
  //   d_ws: xb 0..8M | Wqkvt 8..11M | Wot 11..13M ; Yb aliases xb after attn
  char* ob = (char*)d_out;
  char* ws = (char*)d_ws;
  const size_t MB = 1024 * 1024;
  unsigned short* QKVb  = (unsigned short*)(ob);
  unsigned short* xb    = (unsigned short*)(ws);
  unsigned short* Wqkvt = (unsigned short*)(ws + 8 * MB);
  unsigned short* Wot   = (unsigned short*)(ws + 11 * MB);
  unsigned short* Yb    = xb;   // x-content dead after QKV gemm

  conv_f32_to_bf16<<<4096, 256, 0, stream>>>(x, xb, 4096 * 1024);
  // pack W_qkv^T rows: [0,1024) = Wq, [1024,1280) = Wk, [1280,1536) = Wv
  transpose_conv4<<<dim3(32, 32, 4), dim3(32, 8), 0, stream>>>(
      Wq, Wk, Wv, Wo,
      Wqkvt, Wqkvt + (size_t)1024 * 1024, Wqkvt + (size_t)1280 * 1024, Wot);

  // fused QKV projection: [4096][1536] bf16 (768 blocks, XCD-chunked)
  gemm_bt<<<dim3(768), 256, 0, stream>>>(xb, Wqkvt, QKVb, 4096, 1536, 1024, 0);

  // RoPE on Q (x0.125*log2e) + K in one pass
  rope_qk<<<10240, 256, 0, stream>>>(QKVb, cosb, sinb);

  // attention -> Yb bf16 [B*T][1024]  (8-wave q-split blocks)
  attn_fused<<<dim3(512), 512, 0, stream>>>(QKVb, Yb);

  // output projection (fp32, overwrites d_out; 512 blocks, XCD-chunked)
  gemm_bt<<<dim3(512), 256, 0, stream>>>(Yb, Wot, out, 4096, 1024, 1024, 1);
}